// Round 7
// baseline (64.572 us; speedup 1.0000x reference)
//
#include <hip/hip_runtime.h>

// LRNN: h_t = g_t*h_{t-1} + (1-g_t)*x_t along W, (B,H,W,C)=(8,256,256,64) f32.
// R6 = R5 (chunked scan, LDS carry exchange, NT stores) + NONTEMPORAL G loads.
// Discriminating experiment: R5 sits at 396 MB total traffic / 62.6 us
// = 6.33 TB/s total-fabric; unclear if the cap is total traffic or HBM-only.
// NT-G + NT-out makes X (128 MB) the only cacheable stream -> fully
// IC-resident across replays; HBM traffic drops to 256 MB (G + out).
// If dur -> ~45-52 us: HBM-only model (keep optimizing).
// If dur stays ~60-64 us: total-fabric ceiling -> roofline.

#define LRNN_W 256
#define LRNN_C 64
#define CHUNK 16
#define NCHUNK 16  // LRNN_W / CHUNK

__global__ __launch_bounds__(1024, 8) void lrnn_scan_kernel(
    const float* __restrict__ X, const float* __restrict__ G,
    float* __restrict__ out) {
    __shared__ float lA[NCHUNK][LRNN_C];  // per-chunk gate product
    __shared__ float lB[NCHUNK][LRNN_C];  // per-chunk local end state

    const int c = threadIdx.x & (LRNN_C - 1);
    const int k = threadIdx.x >> 6;        // chunk index = wave index, 0..15
    const int row = blockIdx.x;            // 0..2047  (b*H + h)
    const int base = row * (LRNN_W * LRNN_C) + k * (CHUNK * LRNN_C) + c;

    // Pass A: local scan of the chunk (h_in = 0) + running gate product.
    // h_t = hl[t] + ap[t] * h_in for the true incoming state h_in.
    float hl[CHUNK], ap[CHUNK];
    float h = 0.0f, a = 1.0f;
#pragma unroll
    for (int t = 0; t < CHUNK; ++t) {
        const float x = X[base + t * LRNN_C];                          // cached: IC-resident
        const float g = __builtin_nontemporal_load(&G[base + t * LRNN_C]);  // streamed
        h = fmaf(g, h - x, x);  // g*h + (1-g)*x
        a *= g;
        hl[t] = h;
        ap[t] = a;
    }

    // Carry exchange: (A_k, B_k) per (chunk, channel).
    lA[k][c] = a;
    lB[k][c] = h;
    __syncthreads();

    // Compose incoming state for this chunk: fold chunks 0..k-1 in order.
    // k is wave-uniform (chunk == wave) -> no divergence; lanes read
    // consecutive c -> conflict-free LDS.
    float hin = 0.0f;
    for (int j = 0; j < k; ++j)
        hin = fmaf(lA[j][c], hin, lB[j][c]);

    // Pass B: fixup + nontemporal store (don't write-allocate the LLC).
#pragma unroll
    for (int t = 0; t < CHUNK; ++t)
        __builtin_nontemporal_store(fmaf(ap[t], hin, hl[t]),
                                    &out[base + t * LRNN_C]);
}

extern "C" void kernel_launch(void* const* d_in, const int* in_sizes, int n_in,
                              void* d_out, int out_size, void* d_ws, size_t ws_size,
                              hipStream_t stream) {
    const float* X = (const float*)d_in[0];
    const float* G = (const float*)d_in[1];
    float* out = (float*)d_out;

    const int rows = 8 * 256;  // B*H = 2048 blocks, one row per block
    lrnn_scan_kernel<<<rows, NCHUNK * LRNN_C, 0, stream>>>(X, G, out);
}

// Round 8
// 62.416 us; speedup vs baseline: 1.0345x; 1.0345x over previous
//
#include <hip/hip_runtime.h>

// LRNN: h_t = g_t*h_{t-1} + (1-g_t)*x_t along W, (B,H,W,C)=(8,256,256,64) f32.
// R7 = revert to R5 (measured best: 62.6 us). R6's NT-G discriminator proved
// the limiter is TOTAL fabric traffic (~6.3 TB/s read+write combined,
// regardless of IC vs HBM residency): 384 MB logical / 62.6 us = 6.13 TB/s
// = 97% of the 6.29 TB/s copy-bench ceiling. Traffic is algorithmically
// minimal (each input read once, output written once, zero over-fetch).
// Structure: chunked scan, block = 1024 threads = one (b,h) row; thread
// (k,c) scans a 16-elem chunk (local scan + gate prefix, parked in unified
// VGPR/AGPR file), LDS carry exchange, per-thread compose, fixup + NT store
// (NT store avoids write-allocate churn of the capacity-exact 256MB IC: +25%).

#define LRNN_W 256
#define LRNN_C 64
#define CHUNK 16
#define NCHUNK 16  // LRNN_W / CHUNK

__global__ __launch_bounds__(1024, 8) void lrnn_scan_kernel(
    const float* __restrict__ X, const float* __restrict__ G,
    float* __restrict__ out) {
    __shared__ float lA[NCHUNK][LRNN_C];  // per-chunk gate product
    __shared__ float lB[NCHUNK][LRNN_C];  // per-chunk local end state

    const int c = threadIdx.x & (LRNN_C - 1);
    const int k = threadIdx.x >> 6;        // chunk index = wave index, 0..15
    const int row = blockIdx.x;            // 0..2047  (b*H + h)
    const int base = row * (LRNN_W * LRNN_C) + k * (CHUNK * LRNN_C) + c;

    // Pass A: local scan of the chunk (h_in = 0) + running gate product.
    // h_t = hl[t] + ap[t] * h_in for the true incoming state h_in.
    float hl[CHUNK], ap[CHUNK];
    float h = 0.0f, a = 1.0f;
#pragma unroll
    for (int t = 0; t < CHUNK; ++t) {
        const float x = X[base + t * LRNN_C];
        const float g = G[base + t * LRNN_C];
        h = fmaf(g, h - x, x);  // g*h + (1-g)*x
        a *= g;
        hl[t] = h;
        ap[t] = a;
    }

    // Carry exchange: (A_k, B_k) per (chunk, channel).
    lA[k][c] = a;
    lB[k][c] = h;
    __syncthreads();

    // Compose incoming state for this chunk: fold chunks 0..k-1 in order.
    // k is wave-uniform (chunk == wave) -> no divergence; lanes read
    // consecutive c -> conflict-free LDS.
    float hin = 0.0f;
    for (int j = 0; j < k; ++j)
        hin = fmaf(lA[j][c], hin, lB[j][c]);

    // Pass B: fixup + nontemporal store (don't write-allocate the LLC).
#pragma unroll
    for (int t = 0; t < CHUNK; ++t)
        __builtin_nontemporal_store(fmaf(ap[t], hin, hl[t]),
                                    &out[base + t * LRNN_C]);
}

extern "C" void kernel_launch(void* const* d_in, const int* in_sizes, int n_in,
                              void* d_out, int out_size, void* d_ws, size_t ws_size,
                              hipStream_t stream) {
    const float* X = (const float*)d_in[0];
    const float* G = (const float*)d_in[1];
    float* out = (float*)d_out;

    const int rows = 8 * 256;  // B*H = 2048 blocks, one row per block
    lrnn_scan_kernel<<<rows, NCHUNK * LRNN_C, 0, stream>>>(X, G, out);
}